// Round 2
// baseline (449.024 us; speedup 1.0000x reference)
//
#include <hip/hip_runtime.h>

// Wiener filter, x: [16,3,1024,1024] fp32, ksize=7 (hardcoded).
// Two passes:
//   pass<0>: sum of local_var per (b,c) image -> d_ws (48 floats, atomicAdd)
//   pass<1>: recompute local mean/var per pixel (x L3-resident after pass 0),
//            apply Wiener combine, write out.
// Separable box filter: sliding vertical column sums in registers (add row
// r+3, subtract row r-3 re-read from L1/L2), horizontal 7-tap via LDS row of
// column sums with reflect halos. LDS row buffers are double-buffered so the
// per-row loop needs only ONE __syncthreads().

#define HH 1024
#define WW 1024
#define RB 64            // rows per block strip
#define NT 256           // threads per block (each owns 4 contiguous columns)
#define NIMG 48          // B*C = 16*3
#define STRIPS (HH / RB) // 16

__device__ __forceinline__ int vrefl(int i) {
    // jnp.pad mode='reflect' (no edge repeat): -1 -> 1, 1024 -> 1022
    i = (i < 0) ? -i : i;
    return (i >= HH) ? (2 * HH - 2 - i) : i;
}

__device__ __forceinline__ float4 ld4(const float* p) {
    return *reinterpret_cast<const float4*>(p);
}

template <int FINAL>
__global__ __launch_bounds__(NT) void wiener_pass(const float* __restrict__ x,
                                                  float* __restrict__ nsum,
                                                  float* __restrict__ out) {
    // Double-buffered LDS rows of column sums: [4-halo][1024][4-halo]
    __shared__ __align__(16) float s_cs[2][WW + 8];
    __shared__ __align__(16) float s_c2[2][WW + 8];
    __shared__ float s_red[NT / 64];

    const int t = threadIdx.x;
    const int r0 = blockIdx.x * RB;
    const int bc = blockIdx.y;
    const int c0 = t * 4;

    const float* img = x + (size_t)bc * (HH * WW);

    // --- prologue: column sums of rows r0-3 .. r0+2 (6 rows) ---
    float csx = 0.f, csy = 0.f, csz = 0.f, csw = 0.f;
    float c2x = 0.f, c2y = 0.f, c2z = 0.f, c2w = 0.f;
#pragma unroll
    for (int k = -3; k <= 2; ++k) {
        const int rr = vrefl(r0 + k);
        float4 v = ld4(img + (size_t)rr * WW + c0);
        csx += v.x; csy += v.y; csz += v.z; csw += v.w;
        c2x = fmaf(v.x, v.x, c2x); c2y = fmaf(v.y, v.y, c2y);
        c2z = fmaf(v.z, v.z, c2z); c2w = fmaf(v.w, v.w, c2w);
    }

    float np = 0.f;
    if (FINAL) np = nsum[bc] * (1.0f / ((float)HH * (float)WW));
    float vacc = 0.f;
    const float inv = 1.0f / 49.0f;

    float* oimg = FINAL ? (out + (size_t)bc * (HH * WW)) : nullptr;

    for (int r = r0; r < r0 + RB; ++r) {
        const int p = r & 1;
        const int rN = vrefl(r + 3);
        const int rO = vrefl(r - 3);
        float4 nv = ld4(img + (size_t)rN * WW + c0);
        float4 ov = ld4(img + (size_t)rO * WW + c0); // recent, L1/L2-hit
        float4 xv;
        if (FINAL) xv = ld4(img + (size_t)r * WW + c0); // L1/L2-hit

        // slide window down: add row r+3
        csx += nv.x; csy += nv.y; csz += nv.z; csw += nv.w;
        c2x = fmaf(nv.x, nv.x, c2x); c2y = fmaf(nv.y, nv.y, c2y);
        c2z = fmaf(nv.z, nv.z, c2z); c2w = fmaf(nv.w, nv.w, c2w);

        // publish column sums for horizontal pass (buffer p)
        float* cs = s_cs[p];
        float* c2 = s_c2[p];
        reinterpret_cast<float4*>(cs)[t + 1] = make_float4(csx, csy, csz, csw);
        reinterpret_cast<float4*>(c2)[t + 1] = make_float4(c2x, c2y, c2z, c2w);
        if (t == 0) { // left reflect halo: col -1<-1, -2<-2, -3<-3
            cs[0] = csx; cs[1] = csw; cs[2] = csz; cs[3] = csy;
            c2[0] = c2x; c2[1] = c2w; c2[2] = c2z; c2[3] = c2y;
        }
        if (t == NT - 1) { // right reflect halo: 1024<-1022, 1025<-1021, 1026<-1020
            cs[4 + WW] = csz; cs[4 + WW + 1] = csy; cs[4 + WW + 2] = csx; cs[4 + WW + 3] = csw;
            c2[4 + WW] = c2z; c2[4 + WW + 1] = c2y; c2[4 + WW + 2] = c2x; c2[4 + WW + 3] = c2w;
        }
        __syncthreads();

        // horizontal 7-tap: need cols c0-4..c0+7; own 4 already in registers
        float4 la = reinterpret_cast<const float4*>(cs)[t];     // c0-4..c0-1
        float4 lc = reinterpret_cast<const float4*>(cs)[t + 2]; // c0+4..c0+7
        float4 ma = reinterpret_cast<const float4*>(c2)[t];
        float4 mc = reinterpret_cast<const float4*>(c2)[t + 2];

        float s0 = la.y + la.z + la.w + csx + csy + csz + csw; // window @ c0
        float s1 = s0 - la.y + lc.x;
        float s2 = s1 - la.z + lc.y;
        float s3 = s2 - la.w + lc.z;
        float q0 = ma.y + ma.z + ma.w + c2x + c2y + c2z + c2w;
        float q1 = q0 - ma.y + mc.x;
        float q2 = q1 - ma.z + mc.y;
        float q3 = q2 - ma.w + mc.z;

        float m0 = s0 * inv, m1 = s1 * inv, m2 = s2 * inv, m3 = s3 * inv;
        float v0 = fmaf(q0, inv, -m0 * m0);
        float v1 = fmaf(q1, inv, -m1 * m1);
        float v2 = fmaf(q2, inv, -m2 * m2);
        float v3 = fmaf(q3, inv, -m3 * m3);

        if (FINAL) {
            float g0 = 1.0f - np / v0;  // IEEE div (rcp + fixup), matches ref
            float g1 = 1.0f - np / v1;
            float g2 = 1.0f - np / v2;
            float g3 = 1.0f - np / v3;
            float o0 = fmaf(xv.x - m0, g0, m0);
            float o1 = fmaf(xv.y - m1, g1, m1);
            float o2 = fmaf(xv.z - m2, g2, m2);
            float o3 = fmaf(xv.w - m3, g3, m3);
            o0 = (v0 < np) ? m0 : o0;
            o1 = (v1 < np) ? m1 : o1;
            o2 = (v2 < np) ? m2 : o2;
            o3 = (v3 < np) ? m3 : o3;
            *reinterpret_cast<float4*>(oimg + (size_t)r * WW + c0) =
                make_float4(o0, o1, o2, o3);
        } else {
            vacc += (v0 + v1) + (v2 + v3);
        }

        // slide: subtract row r-3 (no trailing barrier — next row uses buffer p^1)
        csx -= ov.x; csy -= ov.y; csz -= ov.z; csw -= ov.w;
        c2x = fmaf(-ov.x, ov.x, c2x); c2y = fmaf(-ov.y, ov.y, c2y);
        c2z = fmaf(-ov.z, ov.z, c2z); c2w = fmaf(-ov.w, ov.w, c2w);
    }

    if (!FINAL) {
        // wave64 shuffle reduce, then 1 atomicAdd per block
#pragma unroll
        for (int off = 32; off > 0; off >>= 1)
            vacc += __shfl_down(vacc, off, 64);
        __syncthreads(); // row-loop LDS fully consumed before s_red reuse
        if ((t & 63) == 0) s_red[t >> 6] = vacc;
        __syncthreads();
        if (t == 0) {
            float b = (s_red[0] + s_red[1]) + (s_red[2] + s_red[3]);
            atomicAdd(&nsum[bc], b);
        }
    }
}

extern "C" void kernel_launch(void* const* d_in, const int* in_sizes, int n_in,
                              void* d_out, int out_size, void* d_ws, size_t ws_size,
                              hipStream_t stream) {
    const float* x = (const float*)d_in[0];
    float* out = (float*)d_out;
    float* nsum = (float*)d_ws; // 48 float accumulators (re-poisoned each call)

    hipMemsetAsync(nsum, 0, NIMG * sizeof(float), stream);

    dim3 grid(STRIPS, NIMG); // 16 x 48 = 768 blocks, 3 per CU, 12 waves/CU
    wiener_pass<0><<<grid, NT, 0, stream>>>(x, nsum, nullptr);
    wiener_pass<1><<<grid, NT, 0, stream>>>(x, nsum, out);
}

// Round 5
// 394.460 us; speedup vs baseline: 1.1383x; 1.1383x over previous
//
#include <hip/hip_runtime.h>

// Wiener filter, x: [16,3,1024,1024] fp32, ksize=7 (hardcoded).
//   pass<0>: noise power. Uses identity  sum(var) = (1/49)*sum(q) - sum(m^2),
//            where sum(q) = weighted sum of x^2 (reflect-pad box coverage
//            weights factorize per axis: 7 interior, (4,8,8,8) at edges).
//            Only the local-mean (cs) path needs the sliding window + LDS.
//   pass<1>: recompute mean/var per pixel, Wiener combine, nontemporal store
//            (keeps x L3-resident: 201MB x + 201MB out > 256MB LLC otherwise).
// Box filter separable: vertical sliding column sums in registers (add row
// r+3, subtract row r-3 re-read from L1/L2), horizontal 7-tap via LDS row of
// column sums with reflect halos; double-buffered -> one barrier per row.

#define HH 1024
#define WW 1024
#define RB 64            // rows per block strip
#define NT 256           // threads per block (each owns 4 contiguous columns)
#define NIMG 48          // B*C = 16*3
#define STRIPS (HH / RB) // 16

typedef float f32x4 __attribute__((ext_vector_type(4))); // clang vector: ok for nontemporal builtins

__device__ __forceinline__ int vrefl(int i) {
    // jnp.pad mode='reflect': -1 -> 1, 1024 -> 1022
    i = (i < 0) ? -i : i;
    return (i >= HH) ? (2 * HH - 2 - i) : i;
}

__device__ __forceinline__ float wvf(int r) {
    // vertical box coverage weight under reflect padding
    if (r <= 3) return (r == 0) ? 4.0f : 8.0f;
    if (r >= HH - 4) return (r == HH - 1) ? 4.0f : 8.0f;
    return 7.0f;
}

__device__ __forceinline__ float4 ld4(const float* p) {
    return *reinterpret_cast<const float4*>(p);
}

template <int FINAL>
__global__ __launch_bounds__(NT) void wiener_pass(const float* __restrict__ x,
                                                  float* __restrict__ nsum,
                                                  float* __restrict__ out) {
    // Double-buffered LDS rows of column sums: [4-halo][1024][4-halo]
    __shared__ __align__(16) float s_cs[2][WW + 8];
    __shared__ __align__(16) float s_c2[FINAL ? 2 : 1][WW + 8]; // unused when !FINAL
    __shared__ float s_red[NT / 64];

    const int t = threadIdx.x;
    const int r0 = blockIdx.x * RB;
    const int bc = blockIdx.y;
    const int c0 = t * 4;

    const float* img = x + (size_t)bc * (HH * WW);

    // horizontal coverage weights for this thread's 4 columns (pass0 only)
    float whx = 7.f, why = 7.f, whz = 7.f, whw = 7.f;
    if (t == 0) { whx = 4.f; why = 8.f; whz = 8.f; whw = 8.f; }
    if (t == NT - 1) { whx = 8.f; why = 8.f; whz = 8.f; whw = 4.f; }

    // --- prologue: column sums of rows r0-3 .. r0+2 (6 rows) ---
    float csx = 0.f, csy = 0.f, csz = 0.f, csw = 0.f;
    float c2x = 0.f, c2y = 0.f, c2z = 0.f, c2w = 0.f; // used only when FINAL
    float sq_acc = 0.f;                               // weighted sum of x^2 (pass0)
#pragma unroll
    for (int k = -3; k <= 2; ++k) {
        const int rr = vrefl(r0 + k);
        float4 v = ld4(img + (size_t)rr * WW + c0);
        csx += v.x; csy += v.y; csz += v.z; csw += v.w;
        if (FINAL) {
            c2x = fmaf(v.x, v.x, c2x); c2y = fmaf(v.y, v.y, c2y);
            c2z = fmaf(v.z, v.z, c2z); c2w = fmaf(v.w, v.w, c2w);
        } else if (k >= 0) {
            // rows r0..r0+2 belong to this strip: accumulate weighted x^2 once
            float d = fmaf(v.x * v.x, whx, fmaf(v.y * v.y, why,
                      fmaf(v.z * v.z, whz, v.w * v.w * whw)));
            sq_acc = fmaf(d, wvf(r0 + k), sq_acc);
        }
    }

    float np = 0.f;
    if (FINAL) np = nsum[bc] * (1.0f / ((float)HH * (float)WW));
    float msq_acc = 0.f;
    const float inv = 1.0f / 49.0f;

    float* oimg = FINAL ? (out + (size_t)bc * (HH * WW)) : nullptr;

    for (int r = r0; r < r0 + RB; ++r) {
        const int p = r & 1;
        const int rN = vrefl(r + 3);
        const int rO = vrefl(r - 3);
        float4 nv = ld4(img + (size_t)rN * WW + c0);
        float4 ov = ld4(img + (size_t)rO * WW + c0); // recent, L1/L2-hit
        float4 xv;
        if (FINAL) xv = ld4(img + (size_t)r * WW + c0); // L2/L3-hit

        // slide window down: add row r+3
        csx += nv.x; csy += nv.y; csz += nv.z; csw += nv.w;
        if (FINAL) {
            c2x = fmaf(nv.x, nv.x, c2x); c2y = fmaf(nv.y, nv.y, c2y);
            c2z = fmaf(nv.z, nv.z, c2z); c2w = fmaf(nv.w, nv.w, c2w);
        } else if (r < r0 + RB - 3) {
            // row r+3 (identity-mapped, in-strip): weighted x^2, exactly once
            float d = fmaf(nv.x * nv.x, whx, fmaf(nv.y * nv.y, why,
                      fmaf(nv.z * nv.z, whz, nv.w * nv.w * whw)));
            sq_acc = fmaf(d, wvf(r + 3), sq_acc);
        }

        // publish column sums for horizontal pass (buffer p)
        float* cs = s_cs[p];
        float* c2 = s_c2[FINAL ? p : 0];
        reinterpret_cast<float4*>(cs)[t + 1] = make_float4(csx, csy, csz, csw);
        if (FINAL)
            reinterpret_cast<float4*>(c2)[t + 1] = make_float4(c2x, c2y, c2z, c2w);
        if (t == 0) { // left reflect halo: col -1<-1, -2<-2, -3<-3
            cs[0] = csx; cs[1] = csw; cs[2] = csz; cs[3] = csy;
            if (FINAL) { c2[0] = c2x; c2[1] = c2w; c2[2] = c2z; c2[3] = c2y; }
        }
        if (t == NT - 1) { // right reflect halo: 1024<-1022, 1025<-1021, 1026<-1020
            cs[4 + WW] = csz; cs[4 + WW + 1] = csy; cs[4 + WW + 2] = csx; cs[4 + WW + 3] = csw;
            if (FINAL) {
                c2[4 + WW] = c2z; c2[4 + WW + 1] = c2y; c2[4 + WW + 2] = c2x; c2[4 + WW + 3] = c2w;
            }
        }
        __syncthreads();

        // horizontal 7-tap: need cols c0-4..c0+7; own 4 already in registers
        float4 la = reinterpret_cast<const float4*>(cs)[t];     // c0-4..c0-1
        float4 lc = reinterpret_cast<const float4*>(cs)[t + 2]; // c0+4..c0+7

        float s0 = la.y + la.z + la.w + csx + csy + csz + csw; // window @ c0
        float s1 = s0 - la.y + lc.x;
        float s2 = s1 - la.z + lc.y;
        float s3 = s2 - la.w + lc.z;
        float m0 = s0 * inv, m1 = s1 * inv, m2 = s2 * inv, m3 = s3 * inv;

        if (FINAL) {
            float4 ma = reinterpret_cast<const float4*>(c2)[t];
            float4 mc = reinterpret_cast<const float4*>(c2)[t + 2];
            float q0 = ma.y + ma.z + ma.w + c2x + c2y + c2z + c2w;
            float q1 = q0 - ma.y + mc.x;
            float q2 = q1 - ma.z + mc.y;
            float q3 = q2 - ma.w + mc.z;
            float v0 = fmaf(q0, inv, -m0 * m0);
            float v1 = fmaf(q1, inv, -m1 * m1);
            float v2 = fmaf(q2, inv, -m2 * m2);
            float v3 = fmaf(q3, inv, -m3 * m3);

            float g0 = 1.0f - np / v0; // IEEE div (rcp + fixup), matches ref
            float g1 = 1.0f - np / v1;
            float g2 = 1.0f - np / v2;
            float g3 = 1.0f - np / v3;
            float o0 = fmaf(xv.x - m0, g0, m0);
            float o1 = fmaf(xv.y - m1, g1, m1);
            float o2 = fmaf(xv.z - m2, g2, m2);
            float o3 = fmaf(xv.w - m3, g3, m3);
            o0 = (v0 < np) ? m0 : o0;
            o1 = (v1 < np) ? m1 : o1;
            o2 = (v2 < np) ? m2 : o2;
            o3 = (v3 < np) ? m3 : o3;
            // nontemporal store: don't let the out-stream evict x from L3
            f32x4 ov4 = {o0, o1, o2, o3};
            __builtin_nontemporal_store(ov4,
                reinterpret_cast<f32x4*>(oimg + (size_t)r * WW + c0));
        } else {
            msq_acc = fmaf(m0, m0, msq_acc);
            msq_acc = fmaf(m1, m1, msq_acc);
            msq_acc = fmaf(m2, m2, msq_acc);
            msq_acc = fmaf(m3, m3, msq_acc);
        }

        // slide: subtract row r-3 (no trailing barrier: next row uses buffer p^1)
        csx -= ov.x; csy -= ov.y; csz -= ov.z; csw -= ov.w;
        if (FINAL) {
            c2x = fmaf(-ov.x, ov.x, c2x); c2y = fmaf(-ov.y, ov.y, c2y);
            c2z = fmaf(-ov.z, ov.z, c2z); c2w = fmaf(-ov.w, ov.w, c2w);
        }
    }

    if (!FINAL) {
        // block partial of sum(var): (1/49)*sum_w(x^2) - sum(m^2)
        float vacc = fmaf(sq_acc, inv, -msq_acc);
#pragma unroll
        for (int off = 32; off > 0; off >>= 1)
            vacc += __shfl_down(vacc, off, 64);
        __syncthreads(); // row-loop LDS fully consumed before s_red reuse
        if ((t & 63) == 0) s_red[t >> 6] = vacc;
        __syncthreads();
        if (t == 0) {
            float b = (s_red[0] + s_red[1]) + (s_red[2] + s_red[3]);
            atomicAdd(&nsum[bc], b);
        }
    }
}

extern "C" void kernel_launch(void* const* d_in, const int* in_sizes, int n_in,
                              void* d_out, int out_size, void* d_ws, size_t ws_size,
                              hipStream_t stream) {
    const float* x = (const float*)d_in[0];
    float* out = (float*)d_out;
    float* nsum = (float*)d_ws; // 48 float accumulators (re-poisoned each call)

    (void)hipMemsetAsync(nsum, 0, NIMG * sizeof(float), stream);

    dim3 grid(STRIPS, NIMG); // 16 x 48 = 768 blocks, 3 per CU, 12 waves/CU
    wiener_pass<0><<<grid, NT, 0, stream>>>(x, nsum, nullptr);
    wiener_pass<1><<<grid, NT, 0, stream>>>(x, nsum, out);
}

// Round 6
// 379.391 us; speedup vs baseline: 1.1835x; 1.0397x over previous
//
#include <hip/hip_runtime.h>

// Wiener filter, x: [16,3,1024,1024] fp32, ksize=7 (hardcoded).
//   pass<0>: noise power partials. sum(var) = (1/49)*sum_w(x^2) - sum(m^2);
//            per-block partial -> d_ws[bc*16+strip]  (no atomics, no memset).
//   pass<1>: recompute mean/var per pixel, Wiener combine, nontemporal store.
// Separable box filter: vertical sliding column sums in registers; the x rows
// needed again (r-3 "old", r "center") come from an 8-deep register queue
// (fully unrolled -> static slots), so each row costs ONE global load.
// Horizontal 7-tap via LDS row of column sums with reflect halos,
// double-buffered -> one barrier per row.

#define HH 1024
#define WW 1024
#define RB 64            // rows per block strip
#define NT 256           // threads per block (each owns 4 contiguous columns)
#define NIMG 48          // B*C = 16*3
#define STRIPS (HH / RB) // 16

typedef float f32x4 __attribute__((ext_vector_type(4)));

__device__ __forceinline__ int vrefl(int i) {
    // jnp.pad mode='reflect': -1 -> 1, 1024 -> 1022
    i = (i < 0) ? -i : i;
    return (i >= HH) ? (2 * HH - 2 - i) : i;
}

__device__ __forceinline__ float wvf(int r) {
    // vertical box coverage weight under reflect padding
    if (r <= 3) return (r == 0) ? 4.0f : 8.0f;
    if (r >= HH - 4) return (r == HH - 1) ? 4.0f : 8.0f;
    return 7.0f;
}

__device__ __forceinline__ float4 ld4(const float* p) {
    return *reinterpret_cast<const float4*>(p);
}

template <int FINAL>
__global__ __launch_bounds__(NT, 3) void wiener_pass(const float* __restrict__ x,
                                                     float* __restrict__ nsum,
                                                     float* __restrict__ out) {
    // Double-buffered LDS rows of column sums: [4-halo][1024][4-halo]
    __shared__ __align__(16) float s_cs[2][WW + 8];
    __shared__ __align__(16) float s_c2[FINAL ? 2 : 1][WW + 8]; // unused when !FINAL
    __shared__ float s_red[NT / 64];

    const int t = threadIdx.x;
    const int r0 = blockIdx.x * RB;
    const int bc = blockIdx.y;
    const int c0 = t * 4;

    const float* img = x + (size_t)bc * (HH * WW);

    // horizontal coverage weights for this thread's 4 columns (pass0 only)
    float whx = 7.f, why = 7.f, whz = 7.f, whw = 7.f;
    if (t == 0) { whx = 4.f; why = 8.f; whz = 8.f; whw = 8.f; }
    if (t == NT - 1) { whx = 8.f; why = 8.f; whz = 8.f; whw = 4.f; }

    // --- register queue: slot k holds x row with (row & 7) == k ---
    // Prologue: rows r0-3..r0+2 -> slots 5,6,7,0,1,2  (r0 % 8 == 0)
    float4 q0, q1, q2, q3, q4, q5, q6, q7;
    q5 = ld4(img + (size_t)vrefl(r0 - 3) * WW + c0);
    q6 = ld4(img + (size_t)vrefl(r0 - 2) * WW + c0);
    q7 = ld4(img + (size_t)vrefl(r0 - 1) * WW + c0);
    q0 = ld4(img + (size_t)(r0 + 0) * WW + c0);
    q1 = ld4(img + (size_t)(r0 + 1) * WW + c0);
    q2 = ld4(img + (size_t)(r0 + 2) * WW + c0);

    float csx = 0.f, csy = 0.f, csz = 0.f, csw = 0.f;
    float c2x = 0.f, c2y = 0.f, c2z = 0.f, c2w = 0.f; // FINAL only
    float sq_acc = 0.f;                               // weighted x^2 (pass0)

#define ACCROW(Q)                                                         \
    csx += Q.x; csy += Q.y; csz += Q.z; csw += Q.w;                       \
    if (FINAL) {                                                          \
        c2x = fmaf(Q.x, Q.x, c2x); c2y = fmaf(Q.y, Q.y, c2y);             \
        c2z = fmaf(Q.z, Q.z, c2z); c2w = fmaf(Q.w, Q.w, c2w);             \
    }
    ACCROW(q5) ACCROW(q6) ACCROW(q7) ACCROW(q0) ACCROW(q1) ACCROW(q2)
#undef ACCROW
    if (!FINAL) { // rows r0..r0+2 are in-strip: weighted x^2, once each
#define SQROW(Q, R)                                                       \
        {                                                                 \
            float d = fmaf(Q.x * Q.x, whx, fmaf(Q.y * Q.y, why,           \
                      fmaf(Q.z * Q.z, whz, Q.w * Q.w * whw)));            \
            sq_acc = fmaf(d, wvf(R), sq_acc);                             \
        }
        SQROW(q0, r0) SQROW(q1, r0 + 1) SQROW(q2, r0 + 2)
#undef SQROW
    }

    float np = 0.f;
    if (FINAL) {
        float s = 0.f;
#pragma unroll
        for (int i = 0; i < STRIPS; ++i) s += nsum[bc * STRIPS + i];
        np = s * (1.0f / ((float)HH * (float)WW));
    }
    float msq_acc = 0.f;
    const float inv = 1.0f / 49.0f;

    float* oimg = FINAL ? (out + (size_t)bc * (HH * WW)) : nullptr;

    // --- main loop: 8 macro-iters x 8 unrolled rows (static queue slots) ---
#define ROWBODY(J, QN, QO, QX)                                                 \
    {                                                                          \
        const int r = rbase + (J);                                             \
        QN = ld4(img + (size_t)vrefl(r + 3) * WW + c0);                        \
        csx += QN.x; csy += QN.y; csz += QN.z; csw += QN.w;                    \
        if (FINAL) {                                                           \
            c2x = fmaf(QN.x, QN.x, c2x); c2y = fmaf(QN.y, QN.y, c2y);          \
            c2z = fmaf(QN.z, QN.z, c2z); c2w = fmaf(QN.w, QN.w, c2w);          \
        } else if (r < r0 + RB - 3) {                                          \
            float d = fmaf(QN.x * QN.x, whx, fmaf(QN.y * QN.y, why,            \
                      fmaf(QN.z * QN.z, whz, QN.w * QN.w * whw)));             \
            sq_acc = fmaf(d, wvf(r + 3), sq_acc);                              \
        }                                                                      \
        float* cs = s_cs[(J) & 1];                                             \
        float* c2 = s_c2[FINAL ? ((J) & 1) : 0];                               \
        reinterpret_cast<float4*>(cs)[t + 1] = make_float4(csx, csy, csz, csw);\
        if (FINAL)                                                             \
            reinterpret_cast<float4*>(c2)[t + 1] =                             \
                make_float4(c2x, c2y, c2z, c2w);                               \
        if (t == 0) {                                                          \
            cs[0] = csx; cs[1] = csw; cs[2] = csz; cs[3] = csy;                \
            if (FINAL) { c2[0] = c2x; c2[1] = c2w; c2[2] = c2z; c2[3] = c2y; } \
        }                                                                      \
        if (t == NT - 1) {                                                     \
            cs[4 + WW] = csz; cs[4 + WW + 1] = csy;                            \
            cs[4 + WW + 2] = csx; cs[4 + WW + 3] = csw;                        \
            if (FINAL) {                                                       \
                c2[4 + WW] = c2z; c2[4 + WW + 1] = c2y;                        \
                c2[4 + WW + 2] = c2x; c2[4 + WW + 3] = c2w;                    \
            }                                                                  \
        }                                                                      \
        __syncthreads();                                                       \
        float4 la = reinterpret_cast<const float4*>(cs)[t];                    \
        float4 lc = reinterpret_cast<const float4*>(cs)[t + 2];                \
        float s0 = la.y + la.z + la.w + csx + csy + csz + csw;                 \
        float s1 = s0 - la.y + lc.x;                                           \
        float s2 = s1 - la.z + lc.y;                                           \
        float s3 = s2 - la.w + lc.z;                                           \
        float m0 = s0 * inv, m1 = s1 * inv, m2 = s2 * inv, m3 = s3 * inv;      \
        if (FINAL) {                                                           \
            float4 ma = reinterpret_cast<const float4*>(c2)[t];                \
            float4 mc = reinterpret_cast<const float4*>(c2)[t + 2];            \
            float u0 = ma.y + ma.z + ma.w + c2x + c2y + c2z + c2w;             \
            float u1 = u0 - ma.y + mc.x;                                       \
            float u2 = u1 - ma.z + mc.y;                                       \
            float u3 = u2 - ma.w + mc.z;                                       \
            float v0 = fmaf(u0, inv, -m0 * m0);                                \
            float v1 = fmaf(u1, inv, -m1 * m1);                                \
            float v2 = fmaf(u2, inv, -m2 * m2);                                \
            float v3 = fmaf(u3, inv, -m3 * m3);                                \
            float g0 = 1.0f - np / v0;                                         \
            float g1 = 1.0f - np / v1;                                         \
            float g2 = 1.0f - np / v2;                                         \
            float g3 = 1.0f - np / v3;                                         \
            float o0 = fmaf(QX.x - m0, g0, m0);                                \
            float o1 = fmaf(QX.y - m1, g1, m1);                                \
            float o2 = fmaf(QX.z - m2, g2, m2);                                \
            float o3 = fmaf(QX.w - m3, g3, m3);                                \
            o0 = (v0 < np) ? m0 : o0;                                          \
            o1 = (v1 < np) ? m1 : o1;                                          \
            o2 = (v2 < np) ? m2 : o2;                                          \
            o3 = (v3 < np) ? m3 : o3;                                          \
            f32x4 ov4 = {o0, o1, o2, o3};                                      \
            __builtin_nontemporal_store(ov4,                                   \
                reinterpret_cast<f32x4*>(oimg + (size_t)r * WW + c0));         \
        } else {                                                               \
            msq_acc = fmaf(m0, m0, msq_acc);                                   \
            msq_acc = fmaf(m1, m1, msq_acc);                                   \
            msq_acc = fmaf(m2, m2, msq_acc);                                   \
            msq_acc = fmaf(m3, m3, msq_acc);                                   \
        }                                                                      \
        csx -= QO.x; csy -= QO.y; csz -= QO.z; csw -= QO.w;                    \
        if (FINAL) {                                                           \
            c2x = fmaf(-QO.x, QO.x, c2x); c2y = fmaf(-QO.y, QO.y, c2y);        \
            c2z = fmaf(-QO.z, QO.z, c2z); c2w = fmaf(-QO.w, QO.w, c2w);        \
        }                                                                      \
    }

    for (int it = 0; it < RB / 8; ++it) {
        const int rbase = r0 + it * 8;
        // slot math: nv -> (J+3)&7, ov -> (J+5)&7, xv -> J
        ROWBODY(0, q3, q5, q0)
        ROWBODY(1, q4, q6, q1)
        ROWBODY(2, q5, q7, q2)
        ROWBODY(3, q6, q0, q3)
        ROWBODY(4, q7, q1, q4)
        ROWBODY(5, q0, q2, q5)
        ROWBODY(6, q1, q3, q6)
        ROWBODY(7, q2, q4, q7)
    }
#undef ROWBODY

    if (!FINAL) {
        // block partial of sum(var): (1/49)*sum_w(x^2) - sum(m^2)
        float vacc = fmaf(sq_acc, inv, -msq_acc);
#pragma unroll
        for (int off = 32; off > 0; off >>= 1)
            vacc += __shfl_down(vacc, off, 64);
        __syncthreads(); // row-loop LDS fully consumed before s_red reuse
        if ((t & 63) == 0) s_red[t >> 6] = vacc;
        __syncthreads();
        if (t == 0) {
            float b = (s_red[0] + s_red[1]) + (s_red[2] + s_red[3]);
            nsum[bc * STRIPS + blockIdx.x] = b; // per-strip partial, no atomic
        }
    }
}

extern "C" void kernel_launch(void* const* d_in, const int* in_sizes, int n_in,
                              void* d_out, int out_size, void* d_ws, size_t ws_size,
                              hipStream_t stream) {
    const float* x = (const float*)d_in[0];
    float* out = (float*)d_out;
    float* nsum = (float*)d_ws; // 48*16 per-strip partials (fully overwritten)

    dim3 grid(STRIPS, NIMG); // 16 x 48 = 768 blocks, 3 per CU, 12 waves/CU
    wiener_pass<0><<<grid, NT, 0, stream>>>(x, nsum, nullptr);
    wiener_pass<1><<<grid, NT, 0, stream>>>(x, nsum, out);
}